// Round 11
// baseline (4382.772 us; speedup 1.0000x reference)
//
#include <hip/hip_runtime.h>
#include <hip/hip_fp16.h>

#define NN 100000
#define EE 3200000
#define FF 128

#define BSZ 98             // dst-bucket size (nodes); LDS accum 98*128*4 = 50KB -> 3 blocks/CU
#define NBD 1024           // ceil(100000/98) = 1021 -> 1024 (covers 100352)
#define CAPD 3584          // mean 3125, +8 sigma
#define NBS 391            // src buckets of 256 nodes
#define CAPS 12288
#define CH_A 8192
#define NB_A ((EE + CH_A - 1) / CH_A)   // 391

typedef _Float16 f16x8 __attribute__((ext_vector_type(8)));
typedef float f32x4 __attribute__((ext_vector_type(4)));

__device__ __forceinline__ unsigned div98(unsigned d) {
  // floor(d/98) for d < 409200: magic 342393 = ceil(2^25/98), err bound d < 2^25/82
  return (unsigned)(((unsigned long long)d * 342393ull) >> 25);
}

// ---------------------------------------------------------------- bin: edges by dst-bucket (packed) + srcs by src-bucket
// packed rec = (d_local << 17) | s   (s < 2^17, d_local < 98 -> 24 bits)
__global__ __launch_bounds__(256) void k_bin(const int* __restrict__ ei,
                                             int* __restrict__ dcur_g,
                                             int* __restrict__ scur_g,
                                             unsigned int* __restrict__ binned,
                                             int* __restrict__ src_binned) {
  __shared__ int hd[NBD];
  __shared__ int cd[NBD];
  __shared__ int hs[NBS];
  __shared__ int cs[NBS];
  int tid = threadIdx.x;
  for (int t = tid; t < NBD; t += 256) hd[t] = 0;
  for (int t = tid; t < NBS; t += 256) hs[t] = 0;
  __syncthreads();
  int base = blockIdx.x * CH_A;
  const int* dst = ei + EE;
#pragma unroll
  for (int k = 0; k < CH_A / 256; ++k) {
    int e = base + k * 256 + tid;
    if (e < EE) {
      atomicAdd(&hs[ei[e] >> 8], 1);
      atomicAdd(&hd[div98((unsigned)dst[e])], 1);
    }
  }
  __syncthreads();
  for (int t = tid; t < NBD; t += 256) cd[t] = (hd[t] > 0) ? atomicAdd(&dcur_g[t], hd[t]) : 0;
  for (int t = tid; t < NBS; t += 256) cs[t] = (hs[t] > 0) ? atomicAdd(&scur_g[t], hs[t]) : 0;
  __syncthreads();
#pragma unroll
  for (int k = 0; k < CH_A / 256; ++k) {
    int e = base + k * 256 + tid;
    if (e < EE) {
      unsigned s = (unsigned)ei[e];
      unsigned d = (unsigned)dst[e];
      unsigned db = div98(d);
      unsigned dl = d - db * 98u;
      int dpos = atomicAdd(&cd[db], 1);
      binned[(size_t)db * CAPD + dpos] = (dl << 17) | s;
      int sb = (int)(s >> 8);
      int spos = atomicAdd(&cs[sb], 1);
      src_binned[(size_t)sb * CAPS + spos] = (int)s;
    }
  }
}

// ---------------------------------------------------------------- src hist -> dout_is
__global__ __launch_bounds__(256) void k_srchist(const int* __restrict__ src_binned,
                                                 const int* __restrict__ scnt,
                                                 float* __restrict__ dout_is) {
  __shared__ int h[256];
  int tid = threadIdx.x;
  int b = blockIdx.x;
  int src0 = b << 8;
  int gbeg = b * CAPS;
  int cnt = scnt[b];
  h[tid] = 0;
  __syncthreads();
  for (int t = tid; t < cnt; t += 256) {
    atomicAdd(&h[src_binned[gbeg + t] - src0], 1);
  }
  __syncthreads();
  int node = src0 + tid;
  if (node < NN) {
    int d = h[tid]; if (d < 1) d = 1;
    dout_is[node] = rsqrtf((float)d);
  }
}

// ---------------------------------------------------------------- W prep: transpose + fp16 cast
__global__ __launch_bounds__(256) void k_wprep(const float* __restrict__ W,
                                               __half* __restrict__ Wt) {
  int t = blockIdx.x * blockDim.x + threadIdx.x;
  if (t >= FF * FF) return;
  int n = t >> 7, k = t & 127;
  Wt[n * FF + k] = __float2half(W[k * FF + n]);
}

// ---------------------------------------------------------------- prescale to fp16 (row-major)
__global__ __launch_bounds__(256) void k_prescale_h(const float* __restrict__ x,
                                                    const float* __restrict__ dout_is,
                                                    __half* __restrict__ xh) {
  int t = blockIdx.x * blockDim.x + threadIdx.x;
  if (t >= NN * (FF / 4)) return;
  int node = t >> 5;
  float sc = dout_is[node];
  float4 v = ((const float4*)x)[t];
  union { __half2 h[2]; uint2 u; } p;
  p.h[0] = __floats2half2_rn(v.x * sc, v.y * sc);
  p.h[1] = __floats2half2_rn(v.z * sc, v.w * sc);
  ((uint2*)xh)[t] = p.u;
}

// ---------------------------------------------------------------- LDS-accumulator aggregation
// block = one 98-node dst bucket (grid-strided, 512 blocks x 2 buckets each, all co-resident).
// Per edge: two 128B-coalesced ushort gathers (cols lane, 64+lane) + two conflict-free
// ds_add_f32 (bank = lane%32, 2-way). deg_in counted in LDS; din_is applied in finalize.
__global__ __launch_bounds__(512) void k_agg_lds(const __half* __restrict__ xh,
                                                 const unsigned int* __restrict__ binned,
                                                 const int* __restrict__ dcnt,
                                                 __half* __restrict__ outh) {
  __shared__ float acc[BSZ][FF];   // 50176B
  __shared__ int deg[BSZ];
  int tid = threadIdx.x;
  int w = tid >> 6;
  int lane = tid & 63;

  for (int b = blockIdx.x; b < NBD; b += gridDim.x) {
    // zero
    for (int t = tid; t < BSZ * FF / 4; t += 512) ((float4*)&acc[0][0])[t] = make_float4(0.f, 0.f, 0.f, 0.f);
    if (tid < BSZ) deg[tid] = 0;
    __syncthreads();

    int gbeg = b * CAPD;
    int cnt = dcnt[b];
    int K = cnt & ~3;
    for (int i = w * 4; i < K; i += 32) {
      uint4 r = *(const uint4*)(binned + gbeg + i);
      unsigned s0 = r.x & 0x1FFFFu, d0 = r.x >> 17;
      unsigned s1 = r.y & 0x1FFFFu, d1 = r.y >> 17;
      unsigned s2 = r.z & 0x1FFFFu, d2 = r.z >> 17;
      unsigned s3 = r.w & 0x1FFFFu, d3 = r.w >> 17;
      const __half* r0 = xh + (size_t)s0 * FF;
      const __half* r1 = xh + (size_t)s1 * FF;
      const __half* r2 = xh + (size_t)s2 * FF;
      const __half* r3 = xh + (size_t)s3 * FF;
      float a0 = __half2float(r0[lane]);
      float b0 = __half2float(r0[64 + lane]);
      float a1 = __half2float(r1[lane]);
      float b1 = __half2float(r1[64 + lane]);
      float a2 = __half2float(r2[lane]);
      float b2 = __half2float(r2[64 + lane]);
      float a3 = __half2float(r3[lane]);
      float b3 = __half2float(r3[64 + lane]);
      if (lane == 0) {
        atomicAdd(&deg[d0], 1); atomicAdd(&deg[d1], 1);
        atomicAdd(&deg[d2], 1); atomicAdd(&deg[d3], 1);
      }
      atomicAdd(&acc[d0][lane], a0); atomicAdd(&acc[d0][64 + lane], b0);
      atomicAdd(&acc[d1][lane], a1); atomicAdd(&acc[d1][64 + lane], b1);
      atomicAdd(&acc[d2][lane], a2); atomicAdd(&acc[d2][64 + lane], b2);
      atomicAdd(&acc[d3][lane], a3); atomicAdd(&acc[d3][64 + lane], b3);
    }
    // tail (< 4 edges)
    for (int i = K + w; i < cnt; i += 8) {
      unsigned rr = binned[gbeg + i];
      unsigned s = rr & 0x1FFFFu, d = rr >> 17;
      const __half* rp = xh + (size_t)s * FF;
      float a = __half2float(rp[lane]);
      float bb = __half2float(rp[64 + lane]);
      if (lane == 0) atomicAdd(&deg[d], 1);
      atomicAdd(&acc[d][lane], a);
      atomicAdd(&acc[d][64 + lane], bb);
    }
    __syncthreads();

    // finalize: thread -> (node n = tid>>2, col quarter q = tid&3)
    int n = tid >> 2, q = tid & 3;
    if (n < BSZ) {
      int node = b * BSZ + n;
      if (node < NN) {
        int dg = deg[n]; if (dg < 1) dg = 1;
        float di = rsqrtf((float)dg);
        int c0 = q * 32;
#pragma unroll
        for (int j0 = 0; j0 < 32; j0 += 8) {
          union { __half2 h[4]; uint4 u; } p;
#pragma unroll
          for (int jj = 0; jj < 4; ++jj) {
            float vx = acc[n][c0 + j0 + 2 * jj] * di;
            float vy = acc[n][c0 + j0 + 2 * jj + 1] * di;
            p.h[jj] = __floats2half2_rn(vx, vy);
          }
          *(uint4*)(outh + (size_t)node * FF + c0 + j0) = p.u;
        }
      }
    }
    __syncthreads();
  }
}

// ---------------------------------------------------------------- MFMA fp16 GEMM + bias + PReLU (BM=128)
__global__ __launch_bounds__(256) void k_gemm_mfma(const __half* __restrict__ X,
                                                   const __half* __restrict__ Wt,
                                                   const float* __restrict__ bias,
                                                   const float* __restrict__ pa,
                                                   const float* __restrict__ postscale,
                                                   int out_half,
                                                   float* __restrict__ outf,
                                                   __half* __restrict__ outh) {
  __shared__ __half Xs[128][FF + 8];
  __shared__ __half Ws[FF][FF + 8];
  int tid = threadIdx.x;
  int row0 = blockIdx.x * 128;

  for (int t = tid; t < 128 * 16; t += 256) {
    int r = t >> 4, c8 = (t & 15) * 8;
    int row = row0 + r;
    uint4 v = make_uint4(0, 0, 0, 0);
    if (row < NN) v = *(const uint4*)(X + (size_t)row * FF + c8);
    *(uint4*)&Xs[r][c8] = v;
  }
  for (int t = tid; t < FF * 16; t += 256) {
    int r = t >> 4, c8 = (t & 15) * 8;
    uint4 v = *(const uint4*)(Wt + r * FF + c8);
    *(uint4*)&Ws[r][c8] = v;
  }
  __syncthreads();

  int wid = tid >> 6;
  int lane = tid & 63;
  int l15 = lane & 15;
  int g = lane >> 4;
  int arow0 = wid * 16 + l15;
  int arow1 = 64 + arow0;

  f32x4 acc[2][8];
#pragma unroll
  for (int h = 0; h < 2; ++h)
#pragma unroll
    for (int n = 0; n < 8; ++n) acc[h][n] = (f32x4){0.f, 0.f, 0.f, 0.f};

  union FU { uint2 u[2]; f16x8 v; };
#pragma unroll
  for (int kk = 0; kk < 4; ++kk) {
    int kb = kk * 32;
    FU a0, a1;
    a0.u[0] = *(const uint2*)&Xs[arow0][kb + 4 * g];
    a0.u[1] = *(const uint2*)&Xs[arow0][kb + 16 + 4 * g];
    a1.u[0] = *(const uint2*)&Xs[arow1][kb + 4 * g];
    a1.u[1] = *(const uint2*)&Xs[arow1][kb + 16 + 4 * g];
#pragma unroll
    for (int n = 0; n < 8; ++n) {
      FU b;
      int wr = n * 16 + l15;
      b.u[0] = *(const uint2*)&Ws[wr][kb + 4 * g];
      b.u[1] = *(const uint2*)&Ws[wr][kb + 16 + 4 * g];
      acc[0][n] = __builtin_amdgcn_mfma_f32_16x16x32_f16(a0.v, b.v, acc[0][n], 0, 0, 0);
      acc[1][n] = __builtin_amdgcn_mfma_f32_16x16x32_f16(a1.v, b.v, acc[1][n], 0, 0, 0);
    }
  }

#pragma unroll
  for (int h = 0; h < 2; ++h) {
#pragma unroll
    for (int n = 0; n < 8; ++n) {
      int col = n * 16 + l15;
      float bb = bias[col];
      float aa = pa[col];
#pragma unroll
      for (int j = 0; j < 4; ++j) {
        int row = row0 + h * 64 + wid * 16 + g * 4 + j;
        if (row < NN) {
          float v = acc[h][n][j] + bb;
          v = v >= 0.f ? v : aa * v;
          if (out_half) {
            v *= postscale[row];
            outh[(size_t)row * FF + col] = __float2half(v);
          } else {
            outf[(size_t)row * FF + col] = v;
          }
        }
      }
    }
  }
}

// ---------------------------------------------------------------- launch
extern "C" void kernel_launch(void* const* d_in, const int* in_sizes, int n_in,
                              void* d_out, int out_size, void* d_ws, size_t ws_size,
                              hipStream_t stream) {
  const float* features = (const float*)d_in[0];
  const int*   ei       = (const int*)d_in[1];
  const float* W1       = (const float*)d_in[2];
  const float* b1       = (const float*)d_in[3];
  const float* W2       = (const float*)d_in[4];
  const float* b2       = (const float*)d_in[5];
  const float* pa       = (const float*)d_in[6];
  float* out = (float*)d_out;

  char* ws = (char*)d_ws;
  size_t off = 0;
  auto alloc = [&](size_t bytes) -> void* {
    void* p = ws + off;
    off += (bytes + 255) & ~(size_t)255;
    return p;
  };
  int*    cur     = (int*)alloc((size_t)(NBD + NBS) * 4);   // dcur | scur (one memset)
  int*    dcur    = cur;
  int*    scur    = cur + NBD;
  float*  dout_is = (float*)alloc((size_t)NN * 4);
  unsigned int* binned = (unsigned int*)alloc((size_t)NBD * CAPD * 4);  // 14.7MB, persistent
  int*    src_binned   = (int*)alloc((size_t)NBS * CAPS * 4);           // 19.2MB
  __half* tmp_h   = (__half*)alloc((size_t)NN * FF * 2);                // 25.6MB
  __half* xh      = (__half*)alloc((size_t)NN * FF * 2);                // 25.6MB
  __half* w1t     = (__half*)alloc((size_t)FF * FF * 2);
  __half* w2t     = (__half*)alloc((size_t)FF * FF * 2);

  (void)hipMemsetAsync(cur, 0, (size_t)(NBD + NBS) * 4, stream);

  // binning + degrees (LDS-binned, fixed-capacity, packed records; no per-node CSR)
  k_bin<<<NB_A, 256, 0, stream>>>(ei, dcur, scur, binned, src_binned);
  k_srchist<<<NBS, 256, 0, stream>>>(src_binned, scur, dout_is);

  // weight prep
  k_wprep<<<(FF * FF + 255) / 256, 256, 0, stream>>>(W1, w1t);
  k_wprep<<<(FF * FF + 255) / 256, 256, 0, stream>>>(W2, w2t);

  // layer 1: prescale->xh ; agg(xh)->tmp_h ; mfma gemm -> xh (fp16, *dout_is)
  k_prescale_h<<<(NN * FF / 4 + 255) / 256, 256, 0, stream>>>(features, dout_is, xh);
  k_agg_lds<<<512, 512, 0, stream>>>(xh, binned, dcur, tmp_h);
  k_gemm_mfma<<<(NN + 127) / 128, 256, 0, stream>>>(tmp_h, w1t, b1, pa, dout_is, 1, nullptr, xh);

  // layer 2: agg(xh)->tmp_h ; mfma gemm -> out (fp32)
  k_agg_lds<<<512, 512, 0, stream>>>(xh, binned, dcur, tmp_h);
  k_gemm_mfma<<<(NN + 127) / 128, 256, 0, stream>>>(tmp_h, w2t, b2, pa, nullptr, 0, out, nullptr);
}

// Round 12
// 2101.976 us; speedup vs baseline: 2.0851x; 2.0851x over previous
//
#include <hip/hip_runtime.h>
#include <hip/hip_fp16.h>

#define NN 100000
#define EE 3200000
#define FF 128

#define NBUK 391           // buckets of 256 dst nodes; bucket = id >> 8
#define CAP 12288          // per-bucket capacity (mean 8184, sigma ~90)
#define CH_A 8192
#define NB_A ((EE + CH_A - 1) / CH_A)   // 391
#define NCH 8              // src chunks of 12500 nodes (3.2MB fp16 rows: fits one XCD L2)
#define CHSZ 12500u
#define NBLK 1024          // agg grid: 4 blocks/CU x 256 CU, all co-resident
#define NW (NBLK * 4)      // 4096 waves
#define NPW 28             // nodes per wave; 4096*28 = 114688 >= NN

typedef _Float16 f16x8 __attribute__((ext_vector_type(8)));
typedef float f32x4 __attribute__((ext_vector_type(4)));

// ---------------------------------------------------------------- bin: edges by dst-bucket (packed) + srcs by src-bucket
// packed rec = ((d&255) << 24) | s   (s < 2^24)
__global__ __launch_bounds__(256) void k_bin(const int* __restrict__ ei,
                                             int* __restrict__ dcur_g,
                                             int* __restrict__ scur_g,
                                             unsigned int* __restrict__ binned,
                                             int* __restrict__ src_binned) {
  __shared__ int hd[NBUK];
  __shared__ int hs[NBUK];
  __shared__ int cd[NBUK];
  __shared__ int cs[NBUK];
  int tid = threadIdx.x;
  for (int t = tid; t < NBUK; t += 256) { hd[t] = 0; hs[t] = 0; }
  __syncthreads();
  int base = blockIdx.x * CH_A;
  const int* dst = ei + EE;
#pragma unroll
  for (int k = 0; k < CH_A / 256; ++k) {
    int e = base + k * 256 + tid;
    if (e < EE) {
      atomicAdd(&hs[ei[e] >> 8], 1);
      atomicAdd(&hd[dst[e] >> 8], 1);
    }
  }
  __syncthreads();
  for (int t = tid; t < NBUK; t += 256) {
    cd[t] = (hd[t] > 0) ? atomicAdd(&dcur_g[t], hd[t]) : 0;
    cs[t] = (hs[t] > 0) ? atomicAdd(&scur_g[t], hs[t]) : 0;
  }
  __syncthreads();
#pragma unroll
  for (int k = 0; k < CH_A / 256; ++k) {
    int e = base + k * 256 + tid;
    if (e < EE) {
      int s = ei[e];
      int d = dst[e];
      int db = d >> 8;
      int dpos = atomicAdd(&cd[db], 1);
      binned[(size_t)db * CAP + dpos] = ((unsigned int)(d & 255) << 24) | (unsigned int)s;
      int sb = s >> 8;
      int spos = atomicAdd(&cs[sb], 1);
      src_binned[(size_t)sb * CAP + spos] = s;
    }
  }
}

// ---------------------------------------------------------------- CSR finalize: [bucket][chunk][node] layout + seg spans
__global__ __launch_bounds__(256) void k_csr(const unsigned int* __restrict__ binned,
                                             const int* __restrict__ dcnt,
                                             int2* __restrict__ seg,
                                             float* __restrict__ din_is,
                                             int* __restrict__ csr_src) {
  __shared__ int h2[256 * NCH];     // [node][chunk] counts (8KB)
  __shared__ int cur2[256 * NCH];   // (8KB)
  __shared__ int sa[256];
  __shared__ int tct[NCH];
  __shared__ int tcb[NCH];
  int tid = threadIdx.x;
  int b = blockIdx.x;
  int gbeg = b * CAP;
  int cnt = dcnt[b];

#pragma unroll
  for (int i = 0; i < NCH; ++i) h2[tid * NCH + i] = 0;
  __syncthreads();
  for (int t = tid; t < cnt; t += 256) {
    unsigned r = binned[gbeg + t];
    unsigned dl = r >> 24;
    unsigned c = (r & 0xFFFFFFu) / CHSZ;
    atomicAdd(&h2[dl * NCH + c], 1);
  }
  __syncthreads();
  // per-chunk: 256-node exclusive scan
  for (int c = 0; c < NCH; ++c) {
    sa[tid] = h2[tid * NCH + c];
    __syncthreads();
    for (int off = 1; off < 256; off <<= 1) {
      int v = (tid >= off) ? sa[tid - off] : 0;
      __syncthreads();
      sa[tid] += v;
      __syncthreads();
    }
    cur2[tid * NCH + c] = sa[tid] - h2[tid * NCH + c];   // excl within chunk
    if (tid == 255) tct[c] = sa[255];                    // chunk total
    __syncthreads();
  }
  if (tid == 0) {
    int run = 0;
    for (int c = 0; c < NCH; ++c) { tcb[c] = run; run += tct[c]; }
  }
  __syncthreads();
  int node = (b << 8) + tid;
  int deg = 0;
#pragma unroll
  for (int c = 0; c < NCH; ++c) {
    int len = h2[tid * NCH + c];
    int beg = gbeg + tcb[c] + cur2[tid * NCH + c];
    cur2[tid * NCH + c] = beg;
    if (node < NN) seg[(size_t)node * NCH + c] = make_int2(beg, beg + len);
    deg += len;
  }
  if (node < NN) {
    int d = deg < 1 ? 1 : deg;
    din_is[node] = rsqrtf((float)d);
  }
  __syncthreads();
  for (int t = tid; t < cnt; t += 256) {
    unsigned r = binned[gbeg + t];
    unsigned dl = r >> 24;
    unsigned s = r & 0xFFFFFFu;
    unsigned c = s / CHSZ;
    int pos = atomicAdd(&cur2[dl * NCH + c], 1);
    csr_src[pos] = (int)s;
  }
}

// ---------------------------------------------------------------- src hist -> dout_is
__global__ __launch_bounds__(256) void k_srchist(const int* __restrict__ src_binned,
                                                 const int* __restrict__ scnt,
                                                 float* __restrict__ dout_is) {
  __shared__ int h[256];
  int tid = threadIdx.x;
  int b = blockIdx.x;
  int src0 = b << 8;
  int gbeg = b * CAP;
  int cnt = scnt[b];
  h[tid] = 0;
  __syncthreads();
  for (int t = tid; t < cnt; t += 256) {
    atomicAdd(&h[src_binned[gbeg + t] - src0], 1);
  }
  __syncthreads();
  int node = src0 + tid;
  if (node < NN) {
    int d = h[tid]; if (d < 1) d = 1;
    dout_is[node] = rsqrtf((float)d);
  }
}

// ---------------------------------------------------------------- W prep: transpose + fp16 cast
__global__ __launch_bounds__(256) void k_wprep(const float* __restrict__ W,
                                               __half* __restrict__ Wt) {
  int t = blockIdx.x * blockDim.x + threadIdx.x;
  if (t >= FF * FF) return;
  int n = t >> 7, k = t & 127;
  Wt[n * FF + k] = __float2half(W[k * FF + n]);
}

// ---------------------------------------------------------------- prescale to fp16
__global__ __launch_bounds__(256) void k_prescale_h(const float* __restrict__ x,
                                                    const float* __restrict__ dout_is,
                                                    __half* __restrict__ xh) {
  int t = blockIdx.x * blockDim.x + threadIdx.x;
  if (t >= NN * (FF / 4)) return;
  int node = t >> 5;
  float sc = dout_is[node];
  float4 v = ((const float4*)x)[t];
  union { __half2 h[2]; uint2 u; } p;
  p.h[0] = __floats2half2_rn(v.x * sc, v.y * sc);
  p.h[1] = __floats2half2_rn(v.z * sc, v.w * sc);
  ((uint2*)xh)[t] = p.u;
}

// ---------------------------------------------------------------- phase-synced pull aggregation
// 8 src-chunk phases; soft barrier (atomic counter + bounded spin) aligns all waves so the
// 3.2MB chunk is L2-resident per XCD. Barrier is PERF-ONLY: timeout path is still correct.
// Register accumulators (static indices); 4 node-streams interleaved for MLP.
__global__ __launch_bounds__(256, 4) void k_agg_sync(const __half* __restrict__ xh,
                                                     const float* __restrict__ din_is,
                                                     const int2* __restrict__ seg,
                                                     const int* __restrict__ csr_src,
                                                     int* __restrict__ bar,
                                                     __half* __restrict__ outh) {
  int wv = (blockIdx.x << 2) | (threadIdx.x >> 6);
  int lane = threadIdx.x & 63;
  int base = wv * NPW;
  float ax[NPW], ay[NPW];
#pragma unroll
  for (int n = 0; n < NPW; ++n) { ax[n] = 0.f; ay[n] = 0.f; }

  for (int c = 0; c < NCH; ++c) {
#pragma unroll
    for (int q = 0; q < NPW / 4; ++q) {
      int n0 = base + q * 4;
      int2 g0 = (n0 + 0 < NN) ? seg[(size_t)(n0 + 0) * NCH + c] : make_int2(0, 0);
      int2 g1 = (n0 + 1 < NN) ? seg[(size_t)(n0 + 1) * NCH + c] : make_int2(0, 0);
      int2 g2 = (n0 + 2 < NN) ? seg[(size_t)(n0 + 2) * NCH + c] : make_int2(0, 0);
      int2 g3 = (n0 + 3 < NN) ? seg[(size_t)(n0 + 3) * NCH + c] : make_int2(0, 0);
      float a0x = 0.f, a0y = 0.f, a1x = 0.f, a1y = 0.f;
      float a2x = 0.f, a2y = 0.f, a3x = 0.f, a3y = 0.f;
      int e0 = g0.x, e1 = g1.x, e2 = g2.x, e3 = g3.x;
      while ((e0 < g0.y) | (e1 < g1.y) | (e2 < g2.y) | (e3 < g3.y)) {
        if (e0 < g0.y) { int s = csr_src[e0++]; float2 v = __half22float2(((const __half2*)(xh + (size_t)s * FF))[lane]); a0x += v.x; a0y += v.y; }
        if (e1 < g1.y) { int s = csr_src[e1++]; float2 v = __half22float2(((const __half2*)(xh + (size_t)s * FF))[lane]); a1x += v.x; a1y += v.y; }
        if (e2 < g2.y) { int s = csr_src[e2++]; float2 v = __half22float2(((const __half2*)(xh + (size_t)s * FF))[lane]); a2x += v.x; a2y += v.y; }
        if (e3 < g3.y) { int s = csr_src[e3++]; float2 v = __half22float2(((const __half2*)(xh + (size_t)s * FF))[lane]); a3x += v.x; a3y += v.y; }
      }
      ax[q * 4 + 0] += a0x; ay[q * 4 + 0] += a0y;
      ax[q * 4 + 1] += a1x; ay[q * 4 + 1] += a1y;
      ax[q * 4 + 2] += a2x; ay[q * 4 + 2] += a2y;
      ax[q * 4 + 3] += a3x; ay[q * 4 + 3] += a3y;
    }
    if (c < NCH - 1) {
      __syncthreads();
      if (threadIdx.x == 0) {
        __hip_atomic_fetch_add(bar, 1, __ATOMIC_RELAXED, __HIP_MEMORY_SCOPE_AGENT);
        int target = (c + 1) * NBLK;
        long long t0 = clock64();
        while (__hip_atomic_load(bar, __ATOMIC_RELAXED, __HIP_MEMORY_SCOPE_AGENT) < target &&
               (clock64() - t0) < 100000) { }
      }
      __syncthreads();
    }
  }

#pragma unroll
  for (int n = 0; n < NPW; ++n) {
    int node = base + n;
    if (node < NN) {
      float di = din_is[node];
      __half2 r = __floats2half2_rn(ax[n] * di, ay[n] * di);
      ((__half2*)(outh + (size_t)node * FF))[lane] = r;
    }
  }
}

// ---------------------------------------------------------------- MFMA fp16 GEMM + bias + PReLU (BM=128)
__global__ __launch_bounds__(256) void k_gemm_mfma(const __half* __restrict__ X,
                                                   const __half* __restrict__ Wt,
                                                   const float* __restrict__ bias,
                                                   const float* __restrict__ pa,
                                                   const float* __restrict__ postscale,
                                                   int out_half,
                                                   float* __restrict__ outf,
                                                   __half* __restrict__ outh) {
  __shared__ __half Xs[128][FF + 8];
  __shared__ __half Ws[FF][FF + 8];
  int tid = threadIdx.x;
  int row0 = blockIdx.x * 128;

  for (int t = tid; t < 128 * 16; t += 256) {
    int r = t >> 4, c8 = (t & 15) * 8;
    int row = row0 + r;
    uint4 v = make_uint4(0, 0, 0, 0);
    if (row < NN) v = *(const uint4*)(X + (size_t)row * FF + c8);
    *(uint4*)&Xs[r][c8] = v;
  }
  for (int t = tid; t < FF * 16; t += 256) {
    int r = t >> 4, c8 = (t & 15) * 8;
    uint4 v = *(const uint4*)(Wt + r * FF + c8);
    *(uint4*)&Ws[r][c8] = v;
  }
  __syncthreads();

  int wid = tid >> 6;
  int lane = tid & 63;
  int l15 = lane & 15;
  int g = lane >> 4;
  int arow0 = wid * 16 + l15;
  int arow1 = 64 + arow0;

  f32x4 acc[2][8];
#pragma unroll
  for (int h = 0; h < 2; ++h)
#pragma unroll
    for (int n = 0; n < 8; ++n) acc[h][n] = (f32x4){0.f, 0.f, 0.f, 0.f};

  union FU { uint2 u[2]; f16x8 v; };
#pragma unroll
  for (int kk = 0; kk < 4; ++kk) {
    int kb = kk * 32;
    FU a0, a1;
    a0.u[0] = *(const uint2*)&Xs[arow0][kb + 4 * g];
    a0.u[1] = *(const uint2*)&Xs[arow0][kb + 16 + 4 * g];
    a1.u[0] = *(const uint2*)&Xs[arow1][kb + 4 * g];
    a1.u[1] = *(const uint2*)&Xs[arow1][kb + 16 + 4 * g];
#pragma unroll
    for (int n = 0; n < 8; ++n) {
      FU b;
      int wr = n * 16 + l15;
      b.u[0] = *(const uint2*)&Ws[wr][kb + 4 * g];
      b.u[1] = *(const uint2*)&Ws[wr][kb + 16 + 4 * g];
      acc[0][n] = __builtin_amdgcn_mfma_f32_16x16x32_f16(a0.v, b.v, acc[0][n], 0, 0, 0);
      acc[1][n] = __builtin_amdgcn_mfma_f32_16x16x32_f16(a1.v, b.v, acc[1][n], 0, 0, 0);
    }
  }

#pragma unroll
  for (int h = 0; h < 2; ++h) {
#pragma unroll
    for (int n = 0; n < 8; ++n) {
      int col = n * 16 + l15;
      float bb = bias[col];
      float aa = pa[col];
#pragma unroll
      for (int j = 0; j < 4; ++j) {
        int row = row0 + h * 64 + wid * 16 + g * 4 + j;
        if (row < NN) {
          float v = acc[h][n][j] + bb;
          v = v >= 0.f ? v : aa * v;
          if (out_half) {
            v *= postscale[row];
            outh[(size_t)row * FF + col] = __float2half(v);
          } else {
            outf[(size_t)row * FF + col] = v;
          }
        }
      }
    }
  }
}

// ---------------------------------------------------------------- launch
extern "C" void kernel_launch(void* const* d_in, const int* in_sizes, int n_in,
                              void* d_out, int out_size, void* d_ws, size_t ws_size,
                              hipStream_t stream) {
  const float* features = (const float*)d_in[0];
  const int*   ei       = (const int*)d_in[1];
  const float* W1       = (const float*)d_in[2];
  const float* b1       = (const float*)d_in[3];
  const float* W2       = (const float*)d_in[4];
  const float* b2       = (const float*)d_in[5];
  const float* pa       = (const float*)d_in[6];
  float* out = (float*)d_out;

  char* ws = (char*)d_ws;
  size_t off = 0;
  auto alloc = [&](size_t bytes) -> void* {
    void* p = ws + off;
    off += (bytes + 255) & ~(size_t)255;
    return p;
  };
  int*    cur     = (int*)alloc((size_t)(2 * NBUK + 2) * 4);   // dcur | scur | 2 barrier counters
  int*    dcur    = cur;
  int*    scur    = cur + NBUK;
  int*    bar     = cur + 2 * NBUK;
  float*  dout_is = (float*)alloc((size_t)NN * 4);
  float*  din_is  = (float*)alloc((size_t)NN * 4);
  int2*   seg     = (int2*)alloc((size_t)NN * NCH * 8);                 // 6.4MB
  int*    csr_src = (int*)alloc((size_t)NBUK * CAP * 4);                // 19.2MB
  unsigned int* binned = (unsigned int*)alloc((size_t)NBUK * CAP * 4);  // 19.2MB
  int*    src_binned   = (int*)alloc((size_t)NBUK * CAP * 4);           // 19.2MB
  __half* tmp_h   = (__half*)alloc((size_t)NN * FF * 2);                // 25.6MB
  __half* xh      = (__half*)alloc((size_t)NN * FF * 2);                // 25.6MB
  __half* w1t     = (__half*)alloc((size_t)FF * FF * 2);
  __half* w2t     = (__half*)alloc((size_t)FF * FF * 2);

  (void)hipMemsetAsync(cur, 0, (size_t)(2 * NBUK + 2) * 4, stream);

  // CSR build + degrees
  k_bin<<<NB_A, 256, 0, stream>>>(ei, dcur, scur, binned, src_binned);
  k_csr<<<NBUK, 256, 0, stream>>>(binned, dcur, seg, din_is, csr_src);
  k_srchist<<<NBUK, 256, 0, stream>>>(src_binned, scur, dout_is);

  // weight prep
  k_wprep<<<(FF * FF + 255) / 256, 256, 0, stream>>>(W1, w1t);
  k_wprep<<<(FF * FF + 255) / 256, 256, 0, stream>>>(W2, w2t);

  // layer 1: prescale->xh ; phase-synced agg -> tmp_h ; mfma gemm -> xh (fp16, *dout_is)
  k_prescale_h<<<(NN * FF / 4 + 255) / 256, 256, 0, stream>>>(features, dout_is, xh);
  k_agg_sync<<<NBLK, 256, 0, stream>>>(xh, din_is, seg, csr_src, bar + 0, tmp_h);
  k_gemm_mfma<<<(NN + 127) / 128, 256, 0, stream>>>(tmp_h, w1t, b1, pa, dout_is, 1, nullptr, xh);

  // layer 2: agg -> tmp_h ; mfma gemm -> out (fp32)
  k_agg_sync<<<NBLK, 256, 0, stream>>>(xh, din_is, seg, csr_src, bar + 1, tmp_h);
  k_gemm_mfma<<<(NN + 127) / 128, 256, 0, stream>>>(tmp_h, w2t, b2, pa, nullptr, 0, out, nullptr);
}

// Round 13
// 434.696 us; speedup vs baseline: 10.0824x; 4.8355x over previous
//
#include <hip/hip_runtime.h>
#include <hip/hip_fp16.h>

#define NN 100000
#define EE 3200000
#define FF 128

#define NBUK 391           // ceil(NN / 256); bucket = id >> 8 (256 nodes per bucket)
#define CAP 12288          // fixed per-bucket capacity (mean 8184, sigma ~90)
#define CH_A 8192          // edges per bin block
#define NB_A ((EE + CH_A - 1) / CH_A)   // 391

typedef _Float16 f16x8 __attribute__((ext_vector_type(8)));
typedef float f32x4 __attribute__((ext_vector_type(4)));

// ---------------------------------------------------------------- bin: edges by dst-bucket (packed) + srcs by src-bucket
// packed rec = ((d&255) << 24) | s   (s < 2^17)
__global__ __launch_bounds__(256) void k_bin(const int* __restrict__ ei,
                                             int* __restrict__ dcur_g,
                                             int* __restrict__ scur_g,
                                             unsigned int* __restrict__ binned,
                                             int* __restrict__ src_binned) {
  __shared__ int hd[NBUK];
  __shared__ int hs[NBUK];
  __shared__ int cd[NBUK];
  __shared__ int cs[NBUK];
  int tid = threadIdx.x;
  for (int t = tid; t < NBUK; t += 256) { hd[t] = 0; hs[t] = 0; }
  __syncthreads();
  int base = blockIdx.x * CH_A;
  const int* dst = ei + EE;
#pragma unroll
  for (int k = 0; k < CH_A / 256; ++k) {
    int e = base + k * 256 + tid;
    if (e < EE) {
      atomicAdd(&hs[ei[e] >> 8], 1);
      atomicAdd(&hd[dst[e] >> 8], 1);
    }
  }
  __syncthreads();
  for (int t = tid; t < NBUK; t += 256) {
    cd[t] = (hd[t] > 0) ? atomicAdd(&dcur_g[t], hd[t]) : 0;
    cs[t] = (hs[t] > 0) ? atomicAdd(&scur_g[t], hs[t]) : 0;
  }
  __syncthreads();
#pragma unroll
  for (int k = 0; k < CH_A / 256; ++k) {
    int e = base + k * 256 + tid;
    if (e < EE) {
      int s = ei[e];
      int d = dst[e];
      int db = d >> 8;
      int dpos = atomicAdd(&cd[db], 1);
      binned[(size_t)db * CAP + dpos] = ((unsigned int)(d & 255) << 24) | (unsigned int)s;
      int sb = s >> 8;
      int spos = atomicAdd(&cs[sb], 1);
      src_binned[(size_t)sb * CAP + spos] = s;
    }
  }
}

// ---------------------------------------------------------------- CSR finalize (LDS-staged, single global read)
__global__ __launch_bounds__(256) void k_csr(const unsigned int* __restrict__ binned,
                                             const int* __restrict__ dcnt,
                                             int2* __restrict__ offs2,
                                             float* __restrict__ din_is,
                                             int* __restrict__ csr_src) {
  __shared__ unsigned int recs[CAP];   // 48KB
  __shared__ int h[256];
  __shared__ int sa[256];
  __shared__ int cur[256];
  int tid = threadIdx.x;
  int b = blockIdx.x;
  int gbeg = b * CAP;
  int cnt = dcnt[b];

  for (int t = tid; t < cnt; t += 256) recs[t] = binned[gbeg + t];
  h[tid] = 0;
  __syncthreads();
  for (int t = tid; t < cnt; t += 256) atomicAdd(&h[recs[t] >> 24], 1);
  __syncthreads();
  sa[tid] = h[tid];
  __syncthreads();
  for (int off = 1; off < 256; off <<= 1) {
    int v = (tid >= off) ? sa[tid - off] : 0;
    __syncthreads();
    sa[tid] += v;
    __syncthreads();
  }
  int deg = h[tid];
  int excl = sa[tid] - deg;
  cur[tid] = gbeg + excl;
  int node = (b << 8) + tid;
  if (node < NN) {
    offs2[node] = make_int2(gbeg + excl, gbeg + excl + deg);
    int d = deg < 1 ? 1 : deg;
    din_is[node] = rsqrtf((float)d);
  }
  __syncthreads();
  for (int t = tid; t < cnt; t += 256) {
    unsigned int r = recs[t];
    int pos = atomicAdd(&cur[r >> 24], 1);
    csr_src[pos] = (int)(r & 0xFFFFFFu);
  }
}

// ---------------------------------------------------------------- src hist -> dout_is
__global__ __launch_bounds__(256) void k_srchist(const int* __restrict__ src_binned,
                                                 const int* __restrict__ scnt,
                                                 float* __restrict__ dout_is) {
  __shared__ int h[256];
  int tid = threadIdx.x;
  int b = blockIdx.x;
  int src0 = b << 8;
  int gbeg = b * CAP;
  int cnt = scnt[b];
  h[tid] = 0;
  __syncthreads();
  for (int t = tid; t < cnt; t += 256) {
    atomicAdd(&h[src_binned[gbeg + t] - src0], 1);
  }
  __syncthreads();
  int node = src0 + tid;
  if (node < NN) {
    int d = h[tid]; if (d < 1) d = 1;
    dout_is[node] = rsqrtf((float)d);
  }
}

// ---------------------------------------------------------------- W prep (both weights, one launch)
__global__ __launch_bounds__(256) void k_wprep2(const float* __restrict__ W1,
                                                const float* __restrict__ W2,
                                                __half* __restrict__ w1t,
                                                __half* __restrict__ w2t) {
  int t = blockIdx.x * blockDim.x + threadIdx.x;
  int which = t >= FF * FF;
  int u = t - which * FF * FF;
  if (u >= FF * FF) return;
  int n = u >> 7, k = u & 127;
  const float* W = which ? W2 : W1;
  __half* Wt = which ? w2t : w1t;
  Wt[n * FF + k] = __float2half(W[k * FF + n]);
}

// ---------------------------------------------------------------- prescale to fp16 (row-major)
__global__ __launch_bounds__(256) void k_prescale_h(const float* __restrict__ x,
                                                    const float* __restrict__ dout_is,
                                                    __half* __restrict__ xh) {
  int t = blockIdx.x * blockDim.x + threadIdx.x;
  if (t >= NN * (FF / 4)) return;
  int node = t >> 5;
  float sc = dout_is[node];
  float4 v = ((const float4*)x)[t];
  union { __half2 h[2]; uint2 u; } p;
  p.h[0] = __floats2half2_rn(v.x * sc, v.y * sc);
  p.h[1] = __floats2half2_rn(v.z * sc, v.w * sc);
  ((uint2*)xh)[t] = p.u;
}

// ---------------------------------------------------------------- pull aggregation (fp16 gather, fp32 accum, fp16 out)
// one wave per node; lane owns 2 cols (half2) -> 256B contiguous per edge; 8 gathers in flight
__global__ __launch_bounds__(256) void k_agg(const __half* __restrict__ xh,
                                             const float* __restrict__ din_is,
                                             const int2* __restrict__ offs2,
                                             const int* __restrict__ csr_src,
                                             __half* __restrict__ outh) {
  int gid = blockIdx.x * blockDim.x + threadIdx.x;
  int node = gid >> 6;
  int lane = threadIdx.x & 63;
  if (node >= NN) return;
  int2 oo = offs2[node];
  int beg = oo.x, end = oo.y;
  float ax = 0.f, ay = 0.f, bx = 0.f, by = 0.f;
  int e = beg;
  for (; e < end && (e & 3); ++e) {
    int s = csr_src[e];
    float2 v = __half22float2(((const __half2*)(xh + (size_t)s * FF))[lane]);
    ax += v.x; ay += v.y;
  }
  for (; e + 8 <= end; e += 8) {
    int4 i0 = *(const int4*)(csr_src + e);
    int4 i1 = *(const int4*)(csr_src + e + 4);
    float2 v0 = __half22float2(((const __half2*)(xh + (size_t)i0.x * FF))[lane]);
    float2 v1 = __half22float2(((const __half2*)(xh + (size_t)i0.y * FF))[lane]);
    float2 v2 = __half22float2(((const __half2*)(xh + (size_t)i0.z * FF))[lane]);
    float2 v3 = __half22float2(((const __half2*)(xh + (size_t)i0.w * FF))[lane]);
    float2 v4 = __half22float2(((const __half2*)(xh + (size_t)i1.x * FF))[lane]);
    float2 v5 = __half22float2(((const __half2*)(xh + (size_t)i1.y * FF))[lane]);
    float2 v6 = __half22float2(((const __half2*)(xh + (size_t)i1.z * FF))[lane]);
    float2 v7 = __half22float2(((const __half2*)(xh + (size_t)i1.w * FF))[lane]);
    ax += v0.x; ay += v0.y; bx += v1.x; by += v1.y;
    ax += v2.x; ay += v2.y; bx += v3.x; by += v3.y;
    ax += v4.x; ay += v4.y; bx += v5.x; by += v5.y;
    ax += v6.x; ay += v6.y; bx += v7.x; by += v7.y;
  }
  for (; e < end; ++e) {
    int s = csr_src[e];
    float2 v = __half22float2(((const __half2*)(xh + (size_t)s * FF))[lane]);
    ax += v.x; ay += v.y;
  }
  float di = din_is[node];
  __half2 r = __floats2half2_rn((ax + bx) * di, (ay + by) * di);
  ((__half2*)(outh + (size_t)node * FF))[lane] = r;
}

// ---------------------------------------------------------------- MFMA fp16 GEMM + bias + PReLU (BM=128)
__global__ __launch_bounds__(256) void k_gemm_mfma(const __half* __restrict__ X,
                                                   const __half* __restrict__ Wt,
                                                   const float* __restrict__ bias,
                                                   const float* __restrict__ pa,
                                                   const float* __restrict__ postscale,
                                                   int out_half,
                                                   float* __restrict__ outf,
                                                   __half* __restrict__ outh) {
  __shared__ __half Xs[128][FF + 8];
  __shared__ __half Ws[FF][FF + 8];
  int tid = threadIdx.x;
  int row0 = blockIdx.x * 128;

  for (int t = tid; t < 128 * 16; t += 256) {
    int r = t >> 4, c8 = (t & 15) * 8;
    int row = row0 + r;
    uint4 v = make_uint4(0, 0, 0, 0);
    if (row < NN) v = *(const uint4*)(X + (size_t)row * FF + c8);
    *(uint4*)&Xs[r][c8] = v;
  }
  for (int t = tid; t < FF * 16; t += 256) {
    int r = t >> 4, c8 = (t & 15) * 8;
    uint4 v = *(const uint4*)(Wt + r * FF + c8);
    *(uint4*)&Ws[r][c8] = v;
  }
  __syncthreads();

  int wid = tid >> 6;
  int lane = tid & 63;
  int l15 = lane & 15;
  int g = lane >> 4;
  int arow0 = wid * 16 + l15;
  int arow1 = 64 + arow0;

  f32x4 acc[2][8];
#pragma unroll
  for (int h = 0; h < 2; ++h)
#pragma unroll
    for (int n = 0; n < 8; ++n) acc[h][n] = (f32x4){0.f, 0.f, 0.f, 0.f};

  union FU { uint2 u[2]; f16x8 v; };
#pragma unroll
  for (int kk = 0; kk < 4; ++kk) {
    int kb = kk * 32;
    FU a0, a1;
    a0.u[0] = *(const uint2*)&Xs[arow0][kb + 4 * g];
    a0.u[1] = *(const uint2*)&Xs[arow0][kb + 16 + 4 * g];
    a1.u[0] = *(const uint2*)&Xs[arow1][kb + 4 * g];
    a1.u[1] = *(const uint2*)&Xs[arow1][kb + 16 + 4 * g];
#pragma unroll
    for (int n = 0; n < 8; ++n) {
      FU b;
      int wr = n * 16 + l15;
      b.u[0] = *(const uint2*)&Ws[wr][kb + 4 * g];
      b.u[1] = *(const uint2*)&Ws[wr][kb + 16 + 4 * g];
      acc[0][n] = __builtin_amdgcn_mfma_f32_16x16x32_f16(a0.v, b.v, acc[0][n], 0, 0, 0);
      acc[1][n] = __builtin_amdgcn_mfma_f32_16x16x32_f16(a1.v, b.v, acc[1][n], 0, 0, 0);
    }
  }

#pragma unroll
  for (int h = 0; h < 2; ++h) {
#pragma unroll
    for (int n = 0; n < 8; ++n) {
      int col = n * 16 + l15;
      float bb = bias[col];
      float aa = pa[col];
#pragma unroll
      for (int j = 0; j < 4; ++j) {
        int row = row0 + h * 64 + wid * 16 + g * 4 + j;
        if (row < NN) {
          float v = acc[h][n][j] + bb;
          v = v >= 0.f ? v : aa * v;
          if (out_half) {
            v *= postscale[row];
            outh[(size_t)row * FF + col] = __float2half(v);
          } else {
            outf[(size_t)row * FF + col] = v;
          }
        }
      }
    }
  }
}

// ---------------------------------------------------------------- launch
extern "C" void kernel_launch(void* const* d_in, const int* in_sizes, int n_in,
                              void* d_out, int out_size, void* d_ws, size_t ws_size,
                              hipStream_t stream) {
  const float* features = (const float*)d_in[0];
  const int*   ei       = (const int*)d_in[1];
  const float* W1       = (const float*)d_in[2];
  const float* b1       = (const float*)d_in[3];
  const float* W2       = (const float*)d_in[4];
  const float* b2       = (const float*)d_in[5];
  const float* pa       = (const float*)d_in[6];
  float* out = (float*)d_out;

  char* ws = (char*)d_ws;
  size_t off = 0;
  auto alloc = [&](size_t bytes) -> void* {
    void* p = ws + off;
    off += (bytes + 255) & ~(size_t)255;
    return p;
  };
  int*    cur     = (int*)alloc((size_t)2 * NBUK * 4);   // dcur | scur (one memset)
  int*    dcur    = cur;
  int*    scur    = cur + NBUK;
  float*  dout_is = (float*)alloc((size_t)NN * 4);
  float*  din_is  = (float*)alloc((size_t)NN * 4);
  int2*   offs2   = (int2*)alloc((size_t)NN * 8);
  int*    csr_src = (int*)alloc((size_t)NBUK * CAP * 4);               // 19.2MB
  unsigned int* binned = (unsigned int*)alloc((size_t)NBUK * CAP * 4); // 19.2MB; dead after k_csr
  int*    src_binned   = (int*)alloc((size_t)NBUK * CAP * 4);          // 19.2MB; dead after k_srchist
  __half* tmp_h   = (__half*)alloc((size_t)NN * FF * 2);               // 25.6MB
  __half* w1t     = (__half*)alloc((size_t)FF * FF * 2);
  __half* w2t     = (__half*)alloc((size_t)FF * FF * 2);
  __half* xh      = (__half*)binned;   // 25.6MB span over binned+src_binned (both dead before prescale)

  (void)hipMemsetAsync(cur, 0, (size_t)2 * NBUK * 4, stream);

  // CSR build + degrees (LDS-binned, fixed-capacity, packed records)
  k_bin<<<NB_A, 256, 0, stream>>>(ei, dcur, scur, binned, src_binned);
  k_csr<<<NBUK, 256, 0, stream>>>(binned, dcur, offs2, din_is, csr_src);
  k_srchist<<<NBUK, 256, 0, stream>>>(src_binned, scur, dout_is);

  // weight prep (both in one launch)
  k_wprep2<<<(2 * FF * FF + 255) / 256, 256, 0, stream>>>(W1, W2, w1t, w2t);

  // layer 1: prescale->xh ; agg(xh)->tmp_h ; mfma gemm -> xh (fp16, *dout_is)
  k_prescale_h<<<(NN * FF / 4 + 255) / 256, 256, 0, stream>>>(features, dout_is, xh);
  k_agg<<<NN / 4, 256, 0, stream>>>(xh, din_is, offs2, csr_src, tmp_h);
  k_gemm_mfma<<<(NN + 127) / 128, 256, 0, stream>>>(tmp_h, w1t, b1, pa, dout_is, 1, nullptr, xh);

  // layer 2: agg(xh)->tmp_h ; mfma gemm -> out (fp32)
  k_agg<<<NN / 4, 256, 0, stream>>>(xh, din_is, offs2, csr_src, tmp_h);
  k_gemm_mfma<<<(NN + 127) / 128, 256, 0, stream>>>(tmp_h, w2t, b2, pa, nullptr, 0, out, nullptr);
}

// Round 15
// 421.474 us; speedup vs baseline: 10.3987x; 1.0314x over previous
//
#include <hip/hip_runtime.h>
#include <hip/hip_fp16.h>

#define NN 100000
#define EE 3200000
#define FF 128

#define NBUK 391           // ceil(NN / 256); bucket = id >> 8 (256 nodes per bucket)
#define CAP 12288          // fixed per-bucket capacity (mean 8184, sigma ~90)
#define CH_A 8192          // edges per bin block
#define NB_A ((EE + CH_A - 1) / CH_A)   // 391

typedef _Float16 f16x8 __attribute__((ext_vector_type(8)));
typedef float f32x4 __attribute__((ext_vector_type(4)));

// ---------------------------------------------------------------- W prep (both weights, one launch) + cursor zeroing
__global__ __launch_bounds__(256) void k_wprep2(const float* __restrict__ W1,
                                                const float* __restrict__ W2,
                                                __half* __restrict__ w1t,
                                                __half* __restrict__ w2t,
                                                int* __restrict__ cur) {
  int tid = threadIdx.x;
  if (blockIdx.x == 0) {
    for (int t = tid; t < 2 * NBUK; t += 256) cur[t] = 0;
  }
  int t = blockIdx.x * blockDim.x + tid;
  int which = t >= FF * FF;
  int u = t - which * FF * FF;
  if (u >= FF * FF) return;
  int n = u >> 7, k = u & 127;
  const float* W = which ? W2 : W1;
  __half* Wt = which ? w2t : w1t;
  Wt[n * FF + k] = __float2half(W[k * FF + n]);
}

// ---------------------------------------------------------------- bin: edges by dst-bucket (packed) + src bytes by src-bucket
// packed rec = ((d&255) << 24) | s   (s < 2^17); src_binned stores (uchar)(s&255)
__global__ __launch_bounds__(256) void k_bin(const int* __restrict__ ei,
                                             int* __restrict__ dcur_g,
                                             int* __restrict__ scur_g,
                                             unsigned int* __restrict__ binned,
                                             unsigned char* __restrict__ src_binned) {
  __shared__ int hd[NBUK];
  __shared__ int hs[NBUK];
  __shared__ int cd[NBUK];
  __shared__ int cs[NBUK];
  int tid = threadIdx.x;
  for (int t = tid; t < NBUK; t += 256) { hd[t] = 0; hs[t] = 0; }
  __syncthreads();
  int base = blockIdx.x * CH_A;
  const int* dst = ei + EE;
#pragma unroll
  for (int k = 0; k < CH_A / 256; ++k) {
    int e = base + k * 256 + tid;
    if (e < EE) {
      atomicAdd(&hs[ei[e] >> 8], 1);
      atomicAdd(&hd[dst[e] >> 8], 1);
    }
  }
  __syncthreads();
  for (int t = tid; t < NBUK; t += 256) {
    cd[t] = (hd[t] > 0) ? atomicAdd(&dcur_g[t], hd[t]) : 0;
    cs[t] = (hs[t] > 0) ? atomicAdd(&scur_g[t], hs[t]) : 0;
  }
  __syncthreads();
#pragma unroll
  for (int k = 0; k < CH_A / 256; ++k) {
    int e = base + k * 256 + tid;
    if (e < EE) {
      int s = ei[e];
      int d = dst[e];
      int db = d >> 8;
      int dpos = atomicAdd(&cd[db], 1);
      binned[(size_t)db * CAP + dpos] = ((unsigned int)(d & 255) << 24) | (unsigned int)s;
      int sb = s >> 8;
      int spos = atomicAdd(&cs[sb], 1);
      src_binned[(size_t)sb * CAP + spos] = (unsigned char)(s & 255);
    }
  }
}

// ---------------------------------------------------------------- CSR finalize + src hist (merged; one block per bucket)
__global__ __launch_bounds__(256) void k_csrsrc(const unsigned int* __restrict__ binned,
                                                const unsigned char* __restrict__ src_binned,
                                                const int* __restrict__ dcnt,
                                                const int* __restrict__ scnt,
                                                int2* __restrict__ offs2,
                                                float* __restrict__ din_is,
                                                float* __restrict__ dout_is,
                                                int* __restrict__ csr_src) {
  __shared__ unsigned int recs[CAP];   // 48KB
  __shared__ int h[256];
  __shared__ int sa[256];
  __shared__ int cur[256];
  __shared__ int hsrc[256];
  int tid = threadIdx.x;
  int b = blockIdx.x;
  int gbeg = b * CAP;
  int cnt = dcnt[b];
  int scnt_b = scnt[b];

  // ---- dst side: stage records, histogram, scan, scatter
  for (int t = tid; t < cnt; t += 256) recs[t] = binned[gbeg + t];
  h[tid] = 0;
  hsrc[tid] = 0;
  __syncthreads();
  for (int t = tid; t < cnt; t += 256) atomicAdd(&h[recs[t] >> 24], 1);
  // src histogram interleaved (independent of dst scan)
  {
    const unsigned char* sb = src_binned + gbeg;
    int k4 = scnt_b & ~3;
    for (int t = tid * 4; t < k4; t += 1024) {
      uchar4 v = *(const uchar4*)(sb + t);
      atomicAdd(&hsrc[v.x], 1); atomicAdd(&hsrc[v.y], 1);
      atomicAdd(&hsrc[v.z], 1); atomicAdd(&hsrc[v.w], 1);
    }
    for (int t = k4 + tid; t < scnt_b; t += 256) atomicAdd(&hsrc[sb[t]], 1);
  }
  __syncthreads();
  sa[tid] = h[tid];
  __syncthreads();
  for (int off = 1; off < 256; off <<= 1) {
    int v = (tid >= off) ? sa[tid - off] : 0;
    __syncthreads();
    sa[tid] += v;
    __syncthreads();
  }
  int deg = h[tid];
  int excl = sa[tid] - deg;
  cur[tid] = gbeg + excl;
  int node = (b << 8) + tid;
  if (node < NN) {
    offs2[node] = make_int2(gbeg + excl, gbeg + excl + deg);
    int d = deg < 1 ? 1 : deg;
    din_is[node] = rsqrtf((float)d);
    int so = hsrc[tid]; if (so < 1) so = 1;
    dout_is[node] = rsqrtf((float)so);
  }
  __syncthreads();
  for (int t = tid; t < cnt; t += 256) {
    unsigned int r = recs[t];
    int pos = atomicAdd(&cur[r >> 24], 1);
    csr_src[pos] = (int)(r & 0xFFFFFFu);
  }
}

// ---------------------------------------------------------------- prescale to fp16 (row-major)
__global__ __launch_bounds__(256) void k_prescale_h(const float* __restrict__ x,
                                                    const float* __restrict__ dout_is,
                                                    __half* __restrict__ xh) {
  int t = blockIdx.x * blockDim.x + threadIdx.x;
  if (t >= NN * (FF / 4)) return;
  int node = t >> 5;
  float sc = dout_is[node];
  float4 v = ((const float4*)x)[t];
  union { __half2 h[2]; uint2 u; } p;
  p.h[0] = __floats2half2_rn(v.x * sc, v.y * sc);
  p.h[1] = __floats2half2_rn(v.z * sc, v.w * sc);
  ((uint2*)xh)[t] = p.u;
}

// ---------------------------------------------------------------- pull aggregation (fp16 gather, fp32 accum, fp16 out)
// one wave per node; lane owns 2 cols (half2) -> 256B contiguous per edge; 8 gathers in flight
__global__ __launch_bounds__(256) void k_agg(const __half* __restrict__ xh,
                                             const float* __restrict__ din_is,
                                             const int2* __restrict__ offs2,
                                             const int* __restrict__ csr_src,
                                             __half* __restrict__ outh) {
  int gid = blockIdx.x * blockDim.x + threadIdx.x;
  int node = gid >> 6;
  int lane = threadIdx.x & 63;
  if (node >= NN) return;
  int2 oo = offs2[node];
  int beg = oo.x, end = oo.y;
  float ax = 0.f, ay = 0.f, bx = 0.f, by = 0.f;
  int e = beg;
  for (; e < end && (e & 3); ++e) {
    int s = csr_src[e];
    float2 v = __half22float2(((const __half2*)(xh + (size_t)s * FF))[lane]);
    ax += v.x; ay += v.y;
  }
  for (; e + 8 <= end; e += 8) {
    int4 i0 = *(const int4*)(csr_src + e);
    int4 i1 = *(const int4*)(csr_src + e + 4);
    float2 v0 = __half22float2(((const __half2*)(xh + (size_t)i0.x * FF))[lane]);
    float2 v1 = __half22float2(((const __half2*)(xh + (size_t)i0.y * FF))[lane]);
    float2 v2 = __half22float2(((const __half2*)(xh + (size_t)i0.z * FF))[lane]);
    float2 v3 = __half22float2(((const __half2*)(xh + (size_t)i0.w * FF))[lane]);
    float2 v4 = __half22float2(((const __half2*)(xh + (size_t)i1.x * FF))[lane]);
    float2 v5 = __half22float2(((const __half2*)(xh + (size_t)i1.y * FF))[lane]);
    float2 v6 = __half22float2(((const __half2*)(xh + (size_t)i1.z * FF))[lane]);
    float2 v7 = __half22float2(((const __half2*)(xh + (size_t)i1.w * FF))[lane]);
    ax += v0.x; ay += v0.y; bx += v1.x; by += v1.y;
    ax += v2.x; ay += v2.y; bx += v3.x; by += v3.y;
    ax += v4.x; ay += v4.y; bx += v5.x; by += v5.y;
    ax += v6.x; ay += v6.y; bx += v7.x; by += v7.y;
  }
  for (; e < end; ++e) {
    int s = csr_src[e];
    float2 v = __half22float2(((const __half2*)(xh + (size_t)s * FF))[lane]);
    ax += v.x; ay += v.y;
  }
  float di = din_is[node];
  __half2 r = __floats2half2_rn((ax + bx) * di, (ay + by) * di);
  ((__half2*)(outh + (size_t)node * FF))[lane] = r;
}

// ---------------------------------------------------------------- MFMA fp16 GEMM + bias + PReLU (BM=128)
__global__ __launch_bounds__(256) void k_gemm_mfma(const __half* __restrict__ X,
                                                   const __half* __restrict__ Wt,
                                                   const float* __restrict__ bias,
                                                   const float* __restrict__ pa,
                                                   const float* __restrict__ postscale,
                                                   int out_half,
                                                   float* __restrict__ outf,
                                                   __half* __restrict__ outh) {
  __shared__ __half Xs[128][FF + 8];
  __shared__ __half Ws[FF][FF + 8];
  int tid = threadIdx.x;
  int row0 = blockIdx.x * 128;

  for (int t = tid; t < 128 * 16; t += 256) {
    int r = t >> 4, c8 = (t & 15) * 8;
    int row = row0 + r;
    uint4 v = make_uint4(0, 0, 0, 0);
    if (row < NN) v = *(const uint4*)(X + (size_t)row * FF + c8);
    *(uint4*)&Xs[r][c8] = v;
  }
  for (int t = tid; t < FF * 16; t += 256) {
    int r = t >> 4, c8 = (t & 15) * 8;
    uint4 v = *(const uint4*)(Wt + r * FF + c8);
    *(uint4*)&Ws[r][c8] = v;
  }
  __syncthreads();

  int wid = tid >> 6;
  int lane = tid & 63;
  int l15 = lane & 15;
  int g = lane >> 4;
  int arow0 = wid * 16 + l15;
  int arow1 = 64 + arow0;

  f32x4 acc[2][8];
#pragma unroll
  for (int h = 0; h < 2; ++h)
#pragma unroll
    for (int n = 0; n < 8; ++n) acc[h][n] = (f32x4){0.f, 0.f, 0.f, 0.f};

  union FU { uint2 u[2]; f16x8 v; };
#pragma unroll
  for (int kk = 0; kk < 4; ++kk) {
    int kb = kk * 32;
    FU a0, a1;
    a0.u[0] = *(const uint2*)&Xs[arow0][kb + 4 * g];
    a0.u[1] = *(const uint2*)&Xs[arow0][kb + 16 + 4 * g];
    a1.u[0] = *(const uint2*)&Xs[arow1][kb + 4 * g];
    a1.u[1] = *(const uint2*)&Xs[arow1][kb + 16 + 4 * g];
#pragma unroll
    for (int n = 0; n < 8; ++n) {
      FU b;
      int wr = n * 16 + l15;
      b.u[0] = *(const uint2*)&Ws[wr][kb + 4 * g];
      b.u[1] = *(const uint2*)&Ws[wr][kb + 16 + 4 * g];
      acc[0][n] = __builtin_amdgcn_mfma_f32_16x16x32_f16(a0.v, b.v, acc[0][n], 0, 0, 0);
      acc[1][n] = __builtin_amdgcn_mfma_f32_16x16x32_f16(a1.v, b.v, acc[1][n], 0, 0, 0);
    }
  }

#pragma unroll
  for (int h = 0; h < 2; ++h) {
#pragma unroll
    for (int n = 0; n < 8; ++n) {
      int col = n * 16 + l15;
      float bb = bias[col];
      float aa = pa[col];
#pragma unroll
      for (int j = 0; j < 4; ++j) {
        int row = row0 + h * 64 + wid * 16 + g * 4 + j;
        if (row < NN) {
          float v = acc[h][n][j] + bb;
          v = v >= 0.f ? v : aa * v;
          if (out_half) {
            v *= postscale[row];
            outh[(size_t)row * FF + col] = __float2half(v);
          } else {
            outf[(size_t)row * FF + col] = v;
          }
        }
      }
    }
  }
}

// ---------------------------------------------------------------- launch
extern "C" void kernel_launch(void* const* d_in, const int* in_sizes, int n_in,
                              void* d_out, int out_size, void* d_ws, size_t ws_size,
                              hipStream_t stream) {
  const float* features = (const float*)d_in[0];
  const int*   ei       = (const int*)d_in[1];
  const float* W1       = (const float*)d_in[2];
  const float* b1       = (const float*)d_in[3];
  const float* W2       = (const float*)d_in[4];
  const float* b2       = (const float*)d_in[5];
  const float* pa       = (const float*)d_in[6];
  float* out = (float*)d_out;

  char* ws = (char*)d_ws;
  size_t off = 0;
  auto alloc = [&](size_t bytes) -> void* {
    void* p = ws + off;
    off += (bytes + 255) & ~(size_t)255;
    return p;
  };
  int*    cur     = (int*)alloc((size_t)2 * NBUK * 4);   // dcur | scur (zeroed in k_wprep2)
  int*    dcur    = cur;
  int*    scur    = cur + NBUK;
  float*  dout_is = (float*)alloc((size_t)NN * 4);
  float*  din_is  = (float*)alloc((size_t)NN * 4);
  int2*   offs2   = (int2*)alloc((size_t)NN * 8);
  int*    csr_src = (int*)alloc((size_t)NBUK * CAP * 4);                    // 19.2MB
  unsigned int*  binned     = (unsigned int*)alloc((size_t)NBUK * CAP * 4); // 19.2MB; dead after k_csrsrc
  unsigned char* src_binned = (unsigned char*)alloc((size_t)NBUK * CAP);    // 4.8MB; dead after k_csrsrc
  __half* xh      = (__half*)alloc((size_t)NN * FF * 2);               // 25.6MB (own allocation —
                                                                       //  r14 bug: aliasing binned span
                                                                       //  overlapped tmp_h by 1.6MB)
  __half* tmp_h   = (__half*)alloc((size_t)NN * FF * 2);               // 25.6MB
  __half* w1t     = (__half*)alloc((size_t)FF * FF * 2);
  __half* w2t     = (__half*)alloc((size_t)FF * FF * 2);

  // weight prep + cursor zeroing (runs before k_bin on-stream)
  k_wprep2<<<(2 * FF * FF + 255) / 256, 256, 0, stream>>>(W1, W2, w1t, w2t, cur);

  // CSR build + degrees (LDS-binned, fixed-capacity, packed records)
  k_bin<<<NB_A, 256, 0, stream>>>(ei, dcur, scur, binned, src_binned);
  k_csrsrc<<<NBUK, 256, 0, stream>>>(binned, src_binned, dcur, scur,
                                     offs2, din_is, dout_is, csr_src);

  // layer 1: prescale->xh ; agg(xh)->tmp_h ; mfma gemm -> xh (fp16, *dout_is)
  k_prescale_h<<<(NN * FF / 4 + 255) / 256, 256, 0, stream>>>(features, dout_is, xh);
  k_agg<<<NN / 4, 256, 0, stream>>>(xh, din_is, offs2, csr_src, tmp_h);
  k_gemm_mfma<<<(NN + 127) / 128, 256, 0, stream>>>(tmp_h, w1t, b1, pa, dout_is, 1, nullptr, xh);

  // layer 2: agg(xh)->tmp_h ; mfma gemm -> out (fp32)
  k_agg<<<NN / 4, 256, 0, stream>>>(xh, din_is, offs2, csr_src, tmp_h);
  k_gemm_mfma<<<(NN + 127) / 128, 256, 0, stream>>>(tmp_h, w2t, b2, pa, nullptr, 0, out, nullptr);
}